// Round 10
// baseline (424.488 us; speedup 1.0000x reference)
//
#include <hip/hip_runtime.h>
#include <math.h>

#define DEVI __device__ __forceinline__

DEVI float rlane(float v, int l) {
    return __builtin_bit_cast(float, __builtin_amdgcn_readlane(__builtin_bit_cast(int, v), l));
}
DEVI float sigf(float v) { return 1.0f / (1.0f + __expf(-v)); }
DEVI float tanh_f(float v) {
    v = fminf(fmaxf(v, -15.0f), 15.0f);
    float e = __expf(2.0f * v);
    return (e - 1.0f) / (e + 1.0f);
}

// ---------------------------------------------------------------------------
// Kernel A: fused (b,t)-independent tables.
//   Qg[d*40+e]  = {kk[d][e], kb[e][d], kb[d][e], bb[d][e]}
//   KBg[d*32+q] = {K[d][2q], K[d][2q+1], B[d][2q], B[d][2q+1]}
//   beta[t]     = (|bw_t|+1e-8)/sum
// ---------------------------------------------------------------------------
__global__ void precompute_kernel(const float* __restrict__ Kg, const float* __restrict__ Bg,
                                  const float* __restrict__ betaw,
                                  float4* __restrict__ Qg, float4* __restrict__ KBg,
                                  float* __restrict__ beta) {
    int job = blockIdx.x * 256 + threadIdx.x;
    if (job < 1600) {
        int d = job / 40, e = job - d * 40;
        const float* kd = Kg + d * 64;
        const float* ke = Kg + e * 64;
        const float* bd = Bg + d * 64;
        const float* be = Bg + e * 64;
        float kk = 0, kbT = 0, kbr = 0, bb = 0;
        for (int u = 0; u < 64; ++u) {
            kk  = fmaf(kd[u], ke[u], kk);
            kbT = fmaf(ke[u], bd[u], kbT);
            kbr = fmaf(kd[u], be[u], kbr);
            bb  = fmaf(bd[u], be[u], bb);
        }
        Qg[job] = make_float4(kk, kbT, kbr, bb);
    } else if (job < 2880) {
        int j2 = job - 1600;
        int d = j2 >> 5, q = j2 & 31;
        KBg[j2] = make_float4(Kg[d * 64 + 2 * q], Kg[d * 64 + 2 * q + 1],
                              Bg[d * 64 + 2 * q], Bg[d * 64 + 2 * q + 1]);
    }
    if (blockIdx.x == 0) {
        int tid = threadIdx.x;
        __shared__ float red[256];
        float av = (tid < 128) ? (fabsf(betaw[tid]) + 1e-8f) : 0.0f;
        red[tid] = av;
        __syncthreads();
        for (int s = 128; s > 0; s >>= 1) {
            if (tid < s) red[tid] += red[tid + s];
            __syncthreads();
        }
        float tot = red[0];
        if (tid < 128) beta[tid] = av / tot;
    }
}

// ---------------------------------------------------------------------------
// Kernel B: BOTH LSTM layers in one kernel, software-pipelined over t
// (proven R8). Group A (waves 0-3) = layer 1 step s; group B = layer 2 step
// s-1. 129 steps, 2 barriers each.
// ---------------------------------------------------------------------------
__global__ __launch_bounds__(512)
void lstm2_kernel(const float* __restrict__ x,
                  const float* __restrict__ W0, const float* __restrict__ U0,
                  const float* __restrict__ b0,
                  const float* __restrict__ W1, const float* __restrict__ U1,
                  const float* __restrict__ b1,
                  float* __restrict__ y) {
    int b = blockIdx.x;
    int tid = threadIdx.x;
    int j = tid & 255;
    int u = tid & 63;
    int lane = tid & 63;
    int grp = __builtin_amdgcn_readfirstlane(tid) >> 8;

    float wcol[64];
    float ucol[64];
    float bj;
    if (grp == 0) {
#pragma unroll
        for (int d = 0; d < 40; ++d) wcol[d] = W0[d * 256 + j];
#pragma unroll
        for (int k = 0; k < 64; ++k) ucol[k] = U0[k * 256 + j];
        bj = b0[j];
    } else {
#pragma unroll
        for (int k = 0; k < 64; ++k) wcol[k] = W1[k * 256 + j];
#pragma unroll
        for (int k = 0; k < 64; ++k) ucol[k] = U1[k * 256 + j];
        bj = b1[j];
    }

    __shared__ float x_lds[128 * 40];
    __shared__ float a_lds[512];
    __shared__ float h1buf[64];
    __shared__ float h2buf[64];
    const float4* xg = (const float4*)(x + (size_t)b * 128 * 40);
    float4* xl = (float4*)x_lds;
    for (int i = tid; i < 128 * 40 / 4; i += 512) xl[i] = xg[i];
    if (tid < 64) { h1buf[tid] = 0.0f; h2buf[tid] = 0.0f; }
    float c1 = 0.0f, c2 = 0.0f;
    __syncthreads();

    int li = (lane < 40) ? lane : 0;
#pragma unroll 1
    for (int s = 0; s <= 128; ++s) {
        float a0 = bj, a1 = 0.0f, a2 = 0.0f, a3 = 0.0f;
        if (grp == 0) {
            if (s < 128) {
                float xv = x_lds[s * 40 + li];
                float hv = h1buf[lane];
#pragma unroll
                for (int d = 0; d < 40; d += 4) {
                    a0 = fmaf(rlane(xv, d), wcol[d], a0);
                    a1 = fmaf(rlane(xv, d + 1), wcol[d + 1], a1);
                    a2 = fmaf(rlane(xv, d + 2), wcol[d + 2], a2);
                    a3 = fmaf(rlane(xv, d + 3), wcol[d + 3], a3);
                }
#pragma unroll
                for (int k = 0; k < 64; k += 4) {
                    a0 = fmaf(rlane(hv, k), ucol[k], a0);
                    a1 = fmaf(rlane(hv, k + 1), ucol[k + 1], a1);
                    a2 = fmaf(rlane(hv, k + 2), ucol[k + 2], a2);
                    a3 = fmaf(rlane(hv, k + 3), ucol[k + 3], a3);
                }
            }
        } else {
            if (s >= 1) {
                float h1x = h1buf[lane];
                float h2v = h2buf[lane];
#pragma unroll
                for (int k = 0; k < 64; k += 4) {
                    a0 = fmaf(rlane(h1x, k), wcol[k], a0);
                    a1 = fmaf(rlane(h1x, k + 1), wcol[k + 1], a1);
                    a2 = fmaf(rlane(h1x, k + 2), wcol[k + 2], a2);
                    a3 = fmaf(rlane(h1x, k + 3), wcol[k + 3], a3);
                }
#pragma unroll
                for (int k = 0; k < 64; k += 4) {
                    a0 = fmaf(rlane(h2v, k), ucol[k], a0);
                    a1 = fmaf(rlane(h2v, k + 1), ucol[k + 1], a1);
                    a2 = fmaf(rlane(h2v, k + 2), ucol[k + 2], a2);
                    a3 = fmaf(rlane(h2v, k + 3), ucol[k + 3], a3);
                }
            }
        }
        float z = (a0 + a1) + (a2 + a3);
        int g = (tid >> 6) & 3;
        float a = (g == 2) ? tanh_f(z) : sigf(z);
        a_lds[tid] = a;
        __syncthreads();
        if (grp == 0) {
            if (tid < 64 && s < 128) {
                float iv = a_lds[u], fv = a_lds[u + 64];
                float gv = a_lds[u + 128], ov = a_lds[u + 192];
                c1 = fmaf(fv, c1, iv * gv);
                h1buf[u] = ov * tanh_f(c1);
            }
        } else {
            if (tid < 320 && s >= 1) {
                float iv = a_lds[256 + u], fv = a_lds[320 + u];
                float gv = a_lds[384 + u], ov = a_lds[448 + u];
                c2 = fmaf(fv, c2, iv * gv);
                float h2 = ov * tanh_f(c2);
                h2buf[u] = h2;
                y[((size_t)b * 128 + (s - 1)) * 64 + u] = h2;
            }
        }
        __syncthreads();
    }
}

// ---------------------------------------------------------------------------
// Kernel C: attention. NS=2 register-GE, scalar x/y/beta loads (R9-proven).
// NEW: KY loop partially unrolled (#pragma unroll 8) to cap in-flight
// ds_read_b128 prefetch VGPRs — targets real allocation <= 170 so the HW
// gives 3 waves/SIMD WITHOUT an occupancy attribute (attributes spill:
// R2/R3/R7). GE/build/backsub stay fully unrolled (A[] must be static).
// ---------------------------------------------------------------------------
__launch_bounds__(256)
__global__ void attn_kernel(const float* __restrict__ xin, const float* __restrict__ yin,
                            const float4* __restrict__ Qg, const float4* __restrict__ KBg,
                            const float* __restrict__ betap, float* __restrict__ zpart) {
    __shared__ float4 sQ4[40 * 41];   // 26.2 KB
    __shared__ float4 sKB4[40 * 33];  // 21.1 KB
    __shared__ float redW[4][64];
    __shared__ float redA[4][64];
    __shared__ float wsf[64];
    __shared__ float asf[64];
    int tid = threadIdx.x;
    for (int i = tid; i < 1600; i += 256) {
        int d = i / 40, e = i - d * 40;
        sQ4[d * 41 + e] = Qg[i];
    }
    for (int i = tid; i < 1280; i += 256) {
        int d = i >> 5, q = i & 31;
        sKB4[d * 33 + q] = KBg[i];
    }
    __syncthreads();

    int b = blockIdx.x >> 2;          // 4 blocks per batch row
    int qq = blockIdx.x & 3;
    int wv = tid >> 6;
    int lane = tid & 63;
    int rl0 = (lane < 40) ? lane : 39;
    const float4* Qrow = sQ4 + rl0 * 41;
    const float4* KBrow = sKB4 + rl0 * 33;

    float2 wsacc = make_float2(0.f, 0.f);
    float2 asacc = make_float2(0.f, 0.f);
    int su = __builtin_amdgcn_readfirstlane(wv);      // wave-uniform wave id
    int t0u = qq * 32 + su * 8;                       // uniform t base
    size_t bt0u = (size_t)b * 128 + t0u;

#pragma unroll 1
    for (int it = 0; it < 4; ++it) {
        // Wave-uniform row pointers -> scalar (SGPR) operand loads
        const float* yr0 = yin + (bt0u + 2 * it) * 64;
        const float* yr1 = yr0 + 64;
        const float* xr0 = xin + (bt0u + 2 * it) * 40;
        const float* xr1 = xr0 + 40;
        float btx = betap[t0u + 2 * it];
        float bty = betap[t0u + 2 * it + 1];

        // Per-lane x values (lane = row d)
        float2 xv;
        xv.x = xr0[rl0];
        xv.y = xr1[rl0];
        if (lane >= 40) { xv.x = 0.f; xv.y = 0.f; }

        // t1 = (K y)_d, t2 = (B y)_d per stream; y via scalar loads.
        // unroll 8: cap LDS-prefetch register pressure (VGPR budget for
        // 3 waves/SIMD) — body has no A[] or readlane, partial unroll safe.
        float2 t1a = make_float2(0.f, 0.f), t1b = t1a, t2a = t1a, t2b = t1a;
#pragma unroll 8
        for (int q = 0; q < 32; ++q) {
            float4 kb = KBrow[q];
            float s0x = yr0[2 * q], s1x = yr0[2 * q + 1];
            float s0y = yr1[2 * q], s1y = yr1[2 * q + 1];
            t1a.x = fmaf(kb.x, s0x, t1a.x); t1a.y = fmaf(kb.x, s0y, t1a.y);
            t1b.x = fmaf(kb.y, s1x, t1b.x); t1b.y = fmaf(kb.y, s1y, t1b.y);
            t2a.x = fmaf(kb.z, s0x, t2a.x); t2a.y = fmaf(kb.z, s0y, t2a.y);
            t2b.x = fmaf(kb.w, s1x, t2b.x); t2b.y = fmaf(kb.w, s1y, t2b.y);
        }

        // Augmented rows; x broadcasts via scalar loads
        float2 A[41];
        A[40].x = fmaf(xv.x, t1a.x + t1b.x, t2a.x + t2b.x);
        A[40].y = fmaf(xv.y, t1a.y + t1b.y, t2a.y + t2b.y);
#pragma unroll
        for (int e = 0; e < 40; ++e) {
            float4 q4 = Qrow[e];
            float sxx = xr0[e];
            float sxy = xr1[e];
            A[e].x = fmaf(sxx, fmaf(xv.x, q4.x, q4.y), fmaf(xv.x, q4.z, q4.w));
            A[e].y = fmaf(sxy, fmaf(xv.y, q4.x, q4.y), fmaf(xv.y, q4.z, q4.w));
        }

        // GE forward elimination (PD Gram, no pivoting), 2 streams interleaved
#pragma unroll
        for (int k = 0; k < 40; ++k) {
            float rpx = __builtin_amdgcn_rcpf(rlane(A[k].x, k));
            float rpy = __builtin_amdgcn_rcpf(rlane(A[k].y, k));
            bool gt = (lane > k);
            float mx = gt ? A[k].x * rpx : 0.f;
            float my = gt ? A[k].y * rpy : 0.f;
#pragma unroll
            for (int jj = k + 1; jj <= 40; ++jj) {
                A[jj].x = fmaf(-mx, rlane(A[jj].x, k), A[jj].x);
                A[jj].y = fmaf(-my, rlane(A[jj].y, k), A[jj].y);
            }
        }

        // Back substitution; pivot reciprocal recomputed (no rpl array)
        float2 acc = A[40];
        float2 alpha = make_float2(0.f, 0.f);
#pragma unroll
        for (int k = 39; k >= 0; --k) {
            float xk = rlane(acc.x, k) * __builtin_amdgcn_rcpf(rlane(A[k].x, k));
            float yk = rlane(acc.y, k) * __builtin_amdgcn_rcpf(rlane(A[k].y, k));
            bool eq = (lane == k);
            alpha.x = eq ? xk : alpha.x;
            alpha.y = eq ? yk : alpha.y;
            acc.x = fmaf(-xk, A[k].x, acc.x);
            acc.y = fmaf(-yk, A[k].y, acc.y);
        }

        wsacc.x = fmaf(btx, alpha.x * xv.x, wsacc.x);
        wsacc.y = fmaf(bty, alpha.y * xv.y, wsacc.y);
        asacc.x = fmaf(btx, alpha.x, asacc.x);
        asacc.y = fmaf(bty, alpha.y, asacc.y);
    }

    redW[wv][lane] = wsacc.x + wsacc.y;
    redA[wv][lane] = asacc.x + asacc.y;
    __syncthreads();
    if (tid < 64) {
        wsf[tid] = (redW[0][tid] + redW[1][tid]) + (redW[2][tid] + redW[3][tid]);
    } else if (tid < 128) {
        int d = tid - 64;
        asf[d] = (redA[0][d] + redA[1][d]) + (redA[2][d] + redA[3][d]);
    }
    __syncthreads();
    if (tid < 64) {
        const float* KBf = (const float*)sKB4;
        int u = tid;
        int off = ((u >> 1) << 2) + (u & 1);
        float z = 0.0f;
#pragma unroll
        for (int d = 0; d < 40; ++d) {
            float kv = KBf[d * 132 + off];
            float bv = KBf[d * 132 + off + 2];
            z = fmaf(wsf[d], kv, z);
            z = fmaf(asf[d], bv, z);
        }
        zpart[((size_t)b * 4 + qq) * 64 + u] = z;
    }
}

// ---------------------------------------------------------------------------
// Kernel D: deterministic final reduce over the 4 quarter-blocks per b.
// ---------------------------------------------------------------------------
__global__ void reduce_kernel(const float* __restrict__ zpart, float* __restrict__ out) {
    int idx = blockIdx.x * 256 + threadIdx.x;  // 16384 = 256*64
    int b = idx >> 6, u = idx & 63;
    const float* zp = zpart + (size_t)b * 4 * 64 + u;
    out[idx] = (zp[0] + zp[64]) + (zp[128] + zp[192]);
}

// ---------------------------------------------------------------------------
extern "C" void kernel_launch(void* const* d_in, const int* in_sizes, int n_in,
                              void* d_out, int out_size, void* d_ws, size_t ws_size,
                              hipStream_t stream) {
    const float* x  = (const float*)d_in[0];
    const float* W0 = (const float*)d_in[1];
    const float* U0 = (const float*)d_in[2];
    const float* b0 = (const float*)d_in[3];
    const float* W1 = (const float*)d_in[4];
    const float* U1 = (const float*)d_in[5];
    const float* b1 = (const float*)d_in[6];
    const float* Kg = (const float*)d_in[7];
    const float* Bg = (const float*)d_in[8];
    const float* bw = (const float*)d_in[9];
    float* out = (float*)d_out;

    float* y     = (float*)d_ws;                   // 2,097,152 f32
    float4* Qg   = (float4*)(y + 256 * 128 * 64);  // 1600 float4
    float4* KBg  = Qg + 1600;                      // 1280 float4
    float* beta  = (float*)(KBg + 1280);           // 128 f32
    float* zpart = beta + 128;                     // 65,536 f32

    precompute_kernel<<<12, 256, 0, stream>>>(Kg, Bg, bw, Qg, KBg, beta);
    lstm2_kernel<<<256, 512, 0, stream>>>(x, W0, U0, b0, W1, U1, b1, y);
    attn_kernel<<<1024, 256, 0, stream>>>(x, y, Qg, KBg, beta, zpart);
    reduce_kernel<<<64, 256, 0, stream>>>(zpart, out);
}

// Round 11
// 348.789 us; speedup vs baseline: 1.2170x; 1.2170x over previous
//
#include <hip/hip_runtime.h>
#include <math.h>

#define DEVI __device__ __forceinline__

DEVI float rlane(float v, int l) {
    return __builtin_bit_cast(float, __builtin_amdgcn_readlane(__builtin_bit_cast(int, v), l));
}
DEVI float sigf(float v) { return 1.0f / (1.0f + __expf(-v)); }
DEVI float tanh_f(float v) {
    v = fminf(fmaxf(v, -15.0f), 15.0f);
    float e = __expf(2.0f * v);
    return (e - 1.0f) / (e + 1.0f);
}

// ---------------------------------------------------------------------------
// Kernel A: fused (b,t)-independent tables.
//   Qg[d*40+e]  = {kk[d][e], kb[e][d], kb[d][e], bb[d][e]}
//   KBg[d*32+q] = {K[d][2q], K[d][2q+1], B[d][2q], B[d][2q+1]}
//   beta[t]     = (|bw_t|+1e-8)/sum
// ---------------------------------------------------------------------------
__global__ void precompute_kernel(const float* __restrict__ Kg, const float* __restrict__ Bg,
                                  const float* __restrict__ betaw,
                                  float4* __restrict__ Qg, float4* __restrict__ KBg,
                                  float* __restrict__ beta) {
    int job = blockIdx.x * 256 + threadIdx.x;
    if (job < 1600) {
        int d = job / 40, e = job - d * 40;
        const float* kd = Kg + d * 64;
        const float* ke = Kg + e * 64;
        const float* bd = Bg + d * 64;
        const float* be = Bg + e * 64;
        float kk = 0, kbT = 0, kbr = 0, bb = 0;
        for (int u = 0; u < 64; ++u) {
            kk  = fmaf(kd[u], ke[u], kk);
            kbT = fmaf(ke[u], bd[u], kbT);
            kbr = fmaf(kd[u], be[u], kbr);
            bb  = fmaf(bd[u], be[u], bb);
        }
        Qg[job] = make_float4(kk, kbT, kbr, bb);
    } else if (job < 2880) {
        int j2 = job - 1600;
        int d = j2 >> 5, q = j2 & 31;
        KBg[j2] = make_float4(Kg[d * 64 + 2 * q], Kg[d * 64 + 2 * q + 1],
                              Bg[d * 64 + 2 * q], Bg[d * 64 + 2 * q + 1]);
    }
    if (blockIdx.x == 0) {
        int tid = threadIdx.x;
        __shared__ float red[256];
        float av = (tid < 128) ? (fabsf(betaw[tid]) + 1e-8f) : 0.0f;
        red[tid] = av;
        __syncthreads();
        for (int s = 128; s > 0; s >>= 1) {
            if (tid < s) red[tid] += red[tid + s];
            __syncthreads();
        }
        float tot = red[0];
        if (tid < 128) beta[tid] = av / tot;
    }
}

// ---------------------------------------------------------------------------
// Kernel B: both LSTM layers, software-pipelined, ONE barrier per step.
// grp A (waves 0-3) = layer 1 step s; grp B (waves 4-7) = layer 2 step s-2
// (2-step lag makes h1buf parity-safe with a single barrier). Post-barrier,
// EVERY thread reads its lane's 4 activated gates and updates wave-replicated
// (c,h) (lane=unit, bit-identical across waves -> deterministic); only one
// tanh post-barrier. h broadcasts are in-register rlane. 130 supersteps.
// ---------------------------------------------------------------------------
__global__ __launch_bounds__(512)
void lstm2_kernel(const float* __restrict__ x,
                  const float* __restrict__ W0, const float* __restrict__ U0,
                  const float* __restrict__ b0,
                  const float* __restrict__ W1, const float* __restrict__ U1,
                  const float* __restrict__ b1,
                  float* __restrict__ y) {
    int b = blockIdx.x;
    int tid = threadIdx.x;
    int j = tid & 255;
    int lane = tid & 63;
    int grp = __builtin_amdgcn_readfirstlane(tid) >> 8;

    float wcol[64];
    float ucol[64];
    float bj;
    if (grp == 0) {
#pragma unroll
        for (int d = 0; d < 40; ++d) wcol[d] = W0[d * 256 + j];
#pragma unroll
        for (int k = 0; k < 64; ++k) ucol[k] = U0[k * 256 + j];
        bj = b0[j];
    } else {
#pragma unroll
        for (int k = 0; k < 64; ++k) wcol[k] = W1[k * 256 + j];
#pragma unroll
        for (int k = 0; k < 64; ++k) ucol[k] = U1[k * 256 + j];
        bj = b1[j];
    }

    __shared__ float x_lds[128 * 40];   // 20 KB
    __shared__ float a_lds[2][512];     // parity-buffered activated gates
    __shared__ float h1buf[2][64];      // layer-1 h for grp B (2-step lag)
    const float4* xg = (const float4*)(x + (size_t)b * 128 * 40);
    float4* xl = (float4*)x_lds;
    for (int i = tid; i < 128 * 40 / 4; i += 512) xl[i] = xg[i];
    if (tid < 128) h1buf[tid >> 6][tid & 63] = 0.0f;
    float c = 0.0f;    // replicated cell state (lane = unit)
    float h = 0.0f;    // replicated hidden state (lane = unit)
    __syncthreads();

    int li = (lane < 40) ? lane : 0;
#pragma unroll 1
    for (int s = 0; s < 130; ++s) {
        int p = s & 1;
        float a0 = bj, a1 = 0.0f, a2 = 0.0f, a3 = 0.0f;
        if (grp == 0) {
            if (s < 128) {
                float xv = x_lds[s * 40 + li];
#pragma unroll
                for (int d = 0; d < 40; d += 4) {
                    a0 = fmaf(rlane(xv, d), wcol[d], a0);
                    a1 = fmaf(rlane(xv, d + 1), wcol[d + 1], a1);
                    a2 = fmaf(rlane(xv, d + 2), wcol[d + 2], a2);
                    a3 = fmaf(rlane(xv, d + 3), wcol[d + 3], a3);
                }
#pragma unroll
                for (int k = 0; k < 64; k += 4) {
                    a0 = fmaf(rlane(h, k), ucol[k], a0);
                    a1 = fmaf(rlane(h, k + 1), ucol[k + 1], a1);
                    a2 = fmaf(rlane(h, k + 2), ucol[k + 2], a2);
                    a3 = fmaf(rlane(h, k + 3), ucol[k + 3], a3);
                }
            }
        } else {
            if (s >= 2) {
                float h1x = h1buf[p][lane];   // h1[s-2], written post-barrier
                                              // s-2; barrier s-1 orders it
#pragma unroll
                for (int k = 0; k < 64; k += 4) {
                    a0 = fmaf(rlane(h1x, k), wcol[k], a0);
                    a1 = fmaf(rlane(h1x, k + 1), wcol[k + 1], a1);
                    a2 = fmaf(rlane(h1x, k + 2), wcol[k + 2], a2);
                    a3 = fmaf(rlane(h1x, k + 3), wcol[k + 3], a3);
                }
#pragma unroll
                for (int k = 0; k < 64; k += 4) {
                    a0 = fmaf(rlane(h, k), ucol[k], a0);
                    a1 = fmaf(rlane(h, k + 1), ucol[k + 1], a1);
                    a2 = fmaf(rlane(h, k + 2), ucol[k + 2], a2);
                    a3 = fmaf(rlane(h, k + 3), ucol[k + 3], a3);
                }
            }
        }
        float z = (a0 + a1) + (a2 + a3);
        int g = (tid >> 6) & 3;
        float a = (g == 2) ? tanh_f(z) : sigf(z);
        a_lds[p][tid] = a;
        __syncthreads();
        if (grp == 0) {
            if (s < 128) {
                const float* pp = &a_lds[p][0];
                float iv = pp[lane], fv = pp[lane + 64];
                float gv = pp[lane + 128], ov = pp[lane + 192];
                c = fmaf(fv, c, iv * gv);
                h = ov * tanh_f(c);
                if (tid < 64) h1buf[p][lane] = h;   // publish for grp B
            }
        } else {
            if (s >= 2) {
                const float* pp = &a_lds[p][256];
                float iv = pp[lane], fv = pp[lane + 64];
                float gv = pp[lane + 128], ov = pp[lane + 192];
                c = fmaf(fv, c, iv * gv);
                h = ov * tanh_f(c);
                if (tid < 320) y[((size_t)b * 128 + (s - 2)) * 64 + lane] = h;
            }
        }
    }
}

// ---------------------------------------------------------------------------
// Kernel C: attention — exact R9 build (198 µs, VALUBusy 67%). NS=2
// register-GE, scalar x/y/beta loads, KY loop FULLY unrolled (partial unroll
// regressed: R10), uncapped (occupancy attributes spill: R2/R3/R7).
// ---------------------------------------------------------------------------
__launch_bounds__(256)
__global__ void attn_kernel(const float* __restrict__ xin, const float* __restrict__ yin,
                            const float4* __restrict__ Qg, const float4* __restrict__ KBg,
                            const float* __restrict__ betap, float* __restrict__ zpart) {
    __shared__ float4 sQ4[40 * 41];   // 26.2 KB
    __shared__ float4 sKB4[40 * 33];  // 21.1 KB
    __shared__ float redW[4][64];
    __shared__ float redA[4][64];
    __shared__ float wsf[64];
    __shared__ float asf[64];
    int tid = threadIdx.x;
    for (int i = tid; i < 1600; i += 256) {
        int d = i / 40, e = i - d * 40;
        sQ4[d * 41 + e] = Qg[i];
    }
    for (int i = tid; i < 1280; i += 256) {
        int d = i >> 5, q = i & 31;
        sKB4[d * 33 + q] = KBg[i];
    }
    __syncthreads();

    int b = blockIdx.x >> 2;          // 4 blocks per batch row
    int qq = blockIdx.x & 3;
    int wv = tid >> 6;
    int lane = tid & 63;
    int rl0 = (lane < 40) ? lane : 39;
    const float4* Qrow = sQ4 + rl0 * 41;
    const float4* KBrow = sKB4 + rl0 * 33;

    float2 wsacc = make_float2(0.f, 0.f);
    float2 asacc = make_float2(0.f, 0.f);
    int su = __builtin_amdgcn_readfirstlane(wv);      // wave-uniform wave id
    int t0u = qq * 32 + su * 8;                       // uniform t base
    size_t bt0u = (size_t)b * 128 + t0u;

#pragma unroll 1
    for (int it = 0; it < 4; ++it) {
        // Wave-uniform row pointers -> scalar (SGPR) operand loads
        const float* yr0 = yin + (bt0u + 2 * it) * 64;
        const float* yr1 = yr0 + 64;
        const float* xr0 = xin + (bt0u + 2 * it) * 40;
        const float* xr1 = xr0 + 40;
        float btx = betap[t0u + 2 * it];
        float bty = betap[t0u + 2 * it + 1];

        // Per-lane x values (lane = row d)
        float2 xv;
        xv.x = xr0[rl0];
        xv.y = xr1[rl0];
        if (lane >= 40) { xv.x = 0.f; xv.y = 0.f; }

        // t1 = (K y)_d, t2 = (B y)_d per stream; y via scalar loads
        float2 t1a = make_float2(0.f, 0.f), t1b = t1a, t2a = t1a, t2b = t1a;
#pragma unroll
        for (int q = 0; q < 32; ++q) {
            float4 kb = KBrow[q];
            float s0x = yr0[2 * q], s1x = yr0[2 * q + 1];
            float s0y = yr1[2 * q], s1y = yr1[2 * q + 1];
            t1a.x = fmaf(kb.x, s0x, t1a.x); t1a.y = fmaf(kb.x, s0y, t1a.y);
            t1b.x = fmaf(kb.y, s1x, t1b.x); t1b.y = fmaf(kb.y, s1y, t1b.y);
            t2a.x = fmaf(kb.z, s0x, t2a.x); t2a.y = fmaf(kb.z, s0y, t2a.y);
            t2b.x = fmaf(kb.w, s1x, t2b.x); t2b.y = fmaf(kb.w, s1y, t2b.y);
        }

        // Augmented rows; x broadcasts via scalar loads
        float2 A[41];
        A[40].x = fmaf(xv.x, t1a.x + t1b.x, t2a.x + t2b.x);
        A[40].y = fmaf(xv.y, t1a.y + t1b.y, t2a.y + t2b.y);
#pragma unroll
        for (int e = 0; e < 40; ++e) {
            float4 q4 = Qrow[e];
            float sxx = xr0[e];
            float sxy = xr1[e];
            A[e].x = fmaf(sxx, fmaf(xv.x, q4.x, q4.y), fmaf(xv.x, q4.z, q4.w));
            A[e].y = fmaf(sxy, fmaf(xv.y, q4.x, q4.y), fmaf(xv.y, q4.z, q4.w));
        }

        // GE forward elimination (PD Gram, no pivoting), 2 streams interleaved
#pragma unroll
        for (int k = 0; k < 40; ++k) {
            float rpx = __builtin_amdgcn_rcpf(rlane(A[k].x, k));
            float rpy = __builtin_amdgcn_rcpf(rlane(A[k].y, k));
            bool gt = (lane > k);
            float mx = gt ? A[k].x * rpx : 0.f;
            float my = gt ? A[k].y * rpy : 0.f;
#pragma unroll
            for (int jj = k + 1; jj <= 40; ++jj) {
                A[jj].x = fmaf(-mx, rlane(A[jj].x, k), A[jj].x);
                A[jj].y = fmaf(-my, rlane(A[jj].y, k), A[jj].y);
            }
        }

        // Back substitution; pivot reciprocal recomputed (no rpl array)
        float2 acc = A[40];
        float2 alpha = make_float2(0.f, 0.f);
#pragma unroll
        for (int k = 39; k >= 0; --k) {
            float xk = rlane(acc.x, k) * __builtin_amdgcn_rcpf(rlane(A[k].x, k));
            float yk = rlane(acc.y, k) * __builtin_amdgcn_rcpf(rlane(A[k].y, k));
            bool eq = (lane == k);
            alpha.x = eq ? xk : alpha.x;
            alpha.y = eq ? yk : alpha.y;
            acc.x = fmaf(-xk, A[k].x, acc.x);
            acc.y = fmaf(-yk, A[k].y, acc.y);
        }

        wsacc.x = fmaf(btx, alpha.x * xv.x, wsacc.x);
        wsacc.y = fmaf(bty, alpha.y * xv.y, wsacc.y);
        asacc.x = fmaf(btx, alpha.x, asacc.x);
        asacc.y = fmaf(bty, alpha.y, asacc.y);
    }

    redW[wv][lane] = wsacc.x + wsacc.y;
    redA[wv][lane] = asacc.x + asacc.y;
    __syncthreads();
    if (tid < 64) {
        wsf[tid] = (redW[0][tid] + redW[1][tid]) + (redW[2][tid] + redW[3][tid]);
    } else if (tid < 128) {
        int d = tid - 64;
        asf[d] = (redA[0][d] + redA[1][d]) + (redA[2][d] + redA[3][d]);
    }
    __syncthreads();
    if (tid < 64) {
        const float* KBf = (const float*)sKB4;
        int u = tid;
        int off = ((u >> 1) << 2) + (u & 1);
        float z = 0.0f;
#pragma unroll
        for (int d = 0; d < 40; ++d) {
            float kv = KBf[d * 132 + off];
            float bv = KBf[d * 132 + off + 2];
            z = fmaf(wsf[d], kv, z);
            z = fmaf(asf[d], bv, z);
        }
        zpart[((size_t)b * 4 + qq) * 64 + u] = z;
    }
}

// ---------------------------------------------------------------------------
// Kernel D: deterministic final reduce over the 4 quarter-blocks per b.
// ---------------------------------------------------------------------------
__global__ void reduce_kernel(const float* __restrict__ zpart, float* __restrict__ out) {
    int idx = blockIdx.x * 256 + threadIdx.x;  // 16384 = 256*64
    int b = idx >> 6, u = idx & 63;
    const float* zp = zpart + (size_t)b * 4 * 64 + u;
    out[idx] = (zp[0] + zp[64]) + (zp[128] + zp[192]);
}

// ---------------------------------------------------------------------------
extern "C" void kernel_launch(void* const* d_in, const int* in_sizes, int n_in,
                              void* d_out, int out_size, void* d_ws, size_t ws_size,
                              hipStream_t stream) {
    const float* x  = (const float*)d_in[0];
    const float* W0 = (const float*)d_in[1];
    const float* U0 = (const float*)d_in[2];
    const float* b0 = (const float*)d_in[3];
    const float* W1 = (const float*)d_in[4];
    const float* U1 = (const float*)d_in[5];
    const float* b1 = (const float*)d_in[6];
    const float* Kg = (const float*)d_in[7];
    const float* Bg = (const float*)d_in[8];
    const float* bw = (const float*)d_in[9];
    float* out = (float*)d_out;

    float* y     = (float*)d_ws;                   // 2,097,152 f32
    float4* Qg   = (float4*)(y + 256 * 128 * 64);  // 1600 float4
    float4* KBg  = Qg + 1600;                      // 1280 float4
    float* beta  = (float*)(KBg + 1280);           // 128 f32
    float* zpart = beta + 128;                     // 65,536 f32

    precompute_kernel<<<12, 256, 0, stream>>>(Kg, Bg, bw, Qg, KBg, beta);
    lstm2_kernel<<<256, 512, 0, stream>>>(x, W0, U0, b0, W1, U1, b1, y);
    attn_kernel<<<1024, 256, 0, stream>>>(x, y, Qg, KBg, beta, zpart);
    reduce_kernel<<<64, 256, 0, stream>>>(zpart, out);
}